// Round 2
// baseline (1604.655 us; speedup 1.0000x reference)
//
#include <hip/hip_runtime.h>

// GCNEncoder: B=32, N=1024, D_IN=1024, D=1024, L=2, D_FF=512
// bf16 MFMA (16x16x32) GEMMs with f32 accumulation; softmax/LN reduce in f32.
// Workspace-adaptive: batch chunk C in {32..1}; floor = 82 MB of scratch.

#define SM_SCALE 0.04419417382415922f  // 1/sqrt(512)

using bf16x8 = __attribute__((ext_vector_type(8))) short;
using f32x4  = __attribute__((ext_vector_type(4))) float;

__device__ __forceinline__ short f2bf(float f) {
  union { float f; unsigned u; } x; x.f = f;
  unsigned r = x.u + 0x7fffu + ((x.u >> 16) & 1u);  // RNE
  return (short)(r >> 16);
}
__device__ __forceinline__ float bf2f(short s) {
  union { unsigned u; float f; } x;
  x.u = ((unsigned)(unsigned short)s) << 16;
  return x.f;
}

typedef const __attribute__((address_space(1))) void* gp1_t;
typedef __attribute__((address_space(3))) void* lp3_t;
__device__ __forceinline__ void ld_lds16(const void* g, void* l) {
  // async global->LDS; LDS dest = wave-uniform base + lane*16
  __builtin_amdgcn_global_load_lds((gp1_t)g, (lp3_t)l, 16, 0, 0);
}

// ---------------- C(bf16) = A (MxK) * Bt^T (Bt NxK row-major), bf16 in, f32 acc
// MODE 0: relu(acc+bias)   MODE 1: acc+bias   MODE 2: acc
template <int MODE>
__global__ __launch_bounds__(256) void gemm_bt(
    const short* __restrict__ A, const short* __restrict__ Bt,
    short* __restrict__ o16, const float* __restrict__ bias,
    int N, int K, long sA, long sB, long sC)
{
  __shared__ __align__(16) short As[128 * 32];
  __shared__ __align__(16) short Bs[128 * 32];
  const int tid  = threadIdx.x;
  const int lane = tid & 63;
  const int wave = tid >> 6;
  const int wm = wave & 1, wn = wave >> 1;
  const int l15 = lane & 15, quad = lane >> 4;
  const long m0 = (long)blockIdx.y * 128;
  const long n0 = (long)blockIdx.x * 128;
  A  += (long)blockIdx.z * sA;
  Bt += (long)blockIdx.z * sB;

  const int srow = tid >> 2;          // 0..63
  const int scol = (tid & 3) * 8;     // 0,8,16,24
  const short* pa0 = A  + (m0 + srow) * K + scol;
  const short* pa1 = pa0 + 64 * (long)K;
  const short* pb0 = Bt + (n0 + srow) * K + scol;
  const short* pb1 = pb0 + 64 * (long)K;
  char* la = (char*)As + wave * 1024;   // wave-uniform LDS base (lane*16 auto)
  char* lb = (char*)Bs + wave * 1024;

  f32x4 acc[4][4];
  const f32x4 z4 = {0.f, 0.f, 0.f, 0.f};
#pragma unroll
  for (int i = 0; i < 4; i++)
#pragma unroll
    for (int j = 0; j < 4; j++) acc[i][j] = z4;

  const int aoff = (wm * 64 + l15) * 32 + quad * 8;
  const int boff = (wn * 64 + l15) * 32 + quad * 8;

  for (int k0 = 0; k0 < K; k0 += 32) {
    __syncthreads();                       // prior frag reads done
    ld_lds16(pa0, la);
    ld_lds16(pa1, la + 4096);
    ld_lds16(pb0, lb);
    ld_lds16(pb1, lb + 4096);
    pa0 += 32; pa1 += 32; pb0 += 32; pb1 += 32;
    __syncthreads();                       // staging drained (vmcnt(0) at barrier)
    bf16x8 af[4], bfr[4];
#pragma unroll
    for (int mt = 0; mt < 4; ++mt) af[mt] = *(const bf16x8*)(As + aoff + mt * 512);
#pragma unroll
    for (int nt = 0; nt < 4; ++nt) bfr[nt] = *(const bf16x8*)(Bs + boff + nt * 512);
#pragma unroll
    for (int mt = 0; mt < 4; ++mt)
#pragma unroll
      for (int nt = 0; nt < 4; ++nt)
        acc[mt][nt] = __builtin_amdgcn_mfma_f32_16x16x32_bf16(af[mt], bfr[nt], acc[mt][nt], 0, 0, 0);
  }

  const long cbase = (long)blockIdx.z * sC;
#pragma unroll
  for (int mt = 0; mt < 4; ++mt) {
#pragma unroll
    for (int nt = 0; nt < 4; ++nt) {
      const long col = n0 + wn * 64 + nt * 16 + l15;
      float bv = 0.f;
      if (MODE <= 1) bv = bias[col];
#pragma unroll
      for (int i = 0; i < 4; i++) {
        const long row = m0 + wm * 64 + mt * 16 + quad * 4 + i;
        float v = acc[mt][nt][i];
        if (MODE <= 1) v += bv;
        if (MODE == 0) v = fmaxf(v, 0.f);
        o16[cbase + row * (long)N + col] = f2bf(v);
      }
    }
  }
}

// ---------------- f32 -> bf16 (exact-count grid: blocks*1024 == n)
__global__ __launch_bounds__(256) void cvt_bf16_k(const float* __restrict__ src,
                                                  short* __restrict__ dst) {
  long i = ((long)blockIdx.x * 256 + threadIdx.x) * 4;
  float4 v = *(const float4*)(src + i);
  short4 o;
  o.x = f2bf(v.x); o.y = f2bf(v.y); o.z = f2bf(v.z); o.w = f2bf(v.w);
  *(short4*)(dst + i) = o;
}

// ---------------- weight convert + transpose: dst[n][k] = bf16(src[k][n])
__global__ __launch_bounds__(256) void wcvt_t(const float* __restrict__ src,
                                              short* __restrict__ dst, int K, int N) {
  __shared__ float tile[32][33];
  int n0 = blockIdx.x * 32, k0 = blockIdx.y * 32;
  int tx = threadIdx.x & 31, ty = threadIdx.x >> 5;
#pragma unroll
  for (int j = 0; j < 4; j++) tile[ty + 8 * j][tx] = src[(long)(k0 + ty + 8 * j) * N + n0 + tx];
  __syncthreads();
#pragma unroll
  for (int j = 0; j < 4; j++) dst[(long)(n0 + ty + 8 * j) * K + k0 + tx] = f2bf(tile[tx][ty + 8 * j]);
}

// ---------------- per-batch bf16 transpose: dst[z][d][i] = src[z][i][d], 1024x1024
__global__ __launch_bounds__(256) void transpose_bf16(const short* __restrict__ src,
                                                      short* __restrict__ dst) {
  __shared__ short tile[64][65];
  long base = (long)blockIdx.z * 1048576L;
  int i0 = blockIdx.y * 64, d0 = blockIdx.x * 64;
  int tx = threadIdx.x & 63, ty4 = threadIdx.x >> 6;
#pragma unroll
  for (int j = 0; j < 16; j++) {
    int r = ty4 + j * 4;
    tile[r][tx] = src[base + (long)(i0 + r) * 1024 + d0 + tx];
  }
  __syncthreads();
#pragma unroll
  for (int j = 0; j < 16; j++) {
    int r = ty4 + j * 4;
    dst[base + (long)(d0 + r) * 1024 + i0 + tx] = tile[tx][r];
  }
}

// ---------------- masked softmax in-place on bf16 scores (scale applied here)
__global__ __launch_bounds__(256) void softmax_mask(short* __restrict__ sc,
                                                    const float* __restrict__ rel) {
  __shared__ float red[8];
  long row = blockIdx.x;
  short* s = sc + row * 1024;
  const float* r = rel + row * 1024;
  int t = threadIdx.x, lane = t & 63, wave = t >> 6;
  float v[4];
  float mx = -3e38f;
#pragma unroll
  for (int j = 0; j < 4; j++) {
    int i = t + 256 * j;
    v[j] = (r[i] != 0.f) ? bf2f(s[i]) * SM_SCALE : -3e38f;
    mx = fmaxf(mx, v[j]);
  }
#pragma unroll
  for (int o = 32; o > 0; o >>= 1) mx = fmaxf(mx, __shfl_xor(mx, o, 64));
  if (lane == 0) red[wave] = mx;
  __syncthreads();
  mx = fmaxf(fmaxf(red[0], red[1]), fmaxf(red[2], red[3]));
  float e[4], sum = 0.f;
#pragma unroll
  for (int j = 0; j < 4; j++) {
    e[j] = (v[j] > -1e38f) ? __expf(v[j] - mx) : 0.f;
    sum += e[j];
  }
#pragma unroll
  for (int o = 32; o > 0; o >>= 1) sum += __shfl_xor(sum, o, 64);
  if (lane == 0) red[4 + wave] = sum;
  __syncthreads();
  sum = red[4] + red[5] + red[6] + red[7];
  float inv = 1.f / sum;
#pragma unroll
  for (int j = 0; j < 4; j++) s[t + 256 * j] = f2bf(e[j] * inv);
}

// ---------------- residual + LayerNorm: y=LN(xb+dlt)*g+b -> xb (bf16, in-place) + o32 (f32)
__global__ __launch_bounds__(256) void ln_res(short* __restrict__ xb,
                                              const short* __restrict__ dlt,
                                              const float* __restrict__ g,
                                              const float* __restrict__ bb,
                                              float* __restrict__ o32) {
  __shared__ float red[8];
  long row = blockIdx.x;
  short* xr = xb + row * 1024;
  const short* dr = dlt + row * 1024;
  float* orow = o32 + row * 1024;
  int t = threadIdx.x, lane = t & 63, wave = t >> 6;
  float y[4], s = 0.f;
#pragma unroll
  for (int j = 0; j < 4; j++) {
    int i = t + 256 * j;
    y[j] = bf2f(xr[i]) + bf2f(dr[i]);
    s += y[j];
  }
#pragma unroll
  for (int o = 32; o > 0; o >>= 1) s += __shfl_xor(s, o, 64);
  if (lane == 0) red[wave] = s;
  __syncthreads();
  s = red[0] + red[1] + red[2] + red[3];
  float mean = s * (1.f / 1024.f);
  float s2 = 0.f;
#pragma unroll
  for (int j = 0; j < 4; j++) { float d = y[j] - mean; s2 += d * d; }
#pragma unroll
  for (int o = 32; o > 0; o >>= 1) s2 += __shfl_xor(s2, o, 64);
  if (lane == 0) red[4 + wave] = s2;
  __syncthreads();
  s2 = red[4] + red[5] + red[6] + red[7];
  float rs = rsqrtf(s2 * (1.f / 1024.f) + 1e-5f);
#pragma unroll
  for (int j = 0; j < 4; j++) {
    int i = t + 256 * j;
    float o = (y[j] - mean) * rs * g[i] + bb[i];
    orow[i] = o;
    xr[i] = f2bf(o);
  }
}

extern "C" void kernel_launch(void* const* d_in, const int* in_sizes, int n_in,
                              void* d_out, int out_size, void* d_ws, size_t ws_size,
                              hipStream_t stream) {
  const float* node = (const float*)d_in[0];
  const float* rel  = (const float*)d_in[1];
  const float* Wemb = (const float*)d_in[2];
  const float* bemb = (const float*)d_in[3];
  const float* Wq   = (const float*)d_in[4];
  const float* bq   = (const float*)d_in[5];
  const float* Wk   = (const float*)d_in[6];
  const float* bk   = (const float*)d_in[7];
  const float* Wc   = (const float*)d_in[8];
  const float* lng  = (const float*)d_in[9];
  const float* lnb  = (const float*)d_in[10];
  float* out = (float*)d_out;

  // choose batch chunk C (largest fitting): need 77594624 + 8388608*C bytes
  int C = 0;
  for (int c = 32; c >= 1; c >>= 1)
    if (77594624ULL + 8388608ULL * (unsigned long long)c <= (unsigned long long)ws_size) { C = c; break; }
  if (C == 0) return;  // cannot run — will fail loudly with stub-like zeros

  char* ws = (char*)d_ws;
  short* xb    = (short*)ws;                    // 32x1024x1024 bf16 (64 MB), persistent x
  short* WembT = (short*)(ws + 67108864);       // [1024][1024]
  short* WqT   = WembT + 1048576;               // 2 x [512][1024]
  short* WkT   = WqT + 1048576;
  short* WcT   = WkT + 1048576;                 // 2 x [1024][1024]
  char* chunk  = ws + 77594624;
  short* xbT  = (short*)chunk;                          // C x 1024x1024 (2C MB)
  short* sc   = (short*)(chunk + (size_t)C * 2097152);  // C x 1024x1024 (scores->attn)
  short* ctx  = (short*)(chunk + (size_t)C * 4194304);  // C x 1024x1024
  short* q    = (short*)(chunk + (size_t)C * 6291456);  // C x 1024x512
  short* k    = q + (size_t)C * 524288;                 // C x 1024x512
  short* ctx2 = q;                                      // alias (q,k dead by then)

  // weight convert+transpose (tiny, once per launch; ws re-poisoned each call)
  wcvt_t<<<dim3(32, 32), 256, 0, stream>>>(Wemb,          WembT,          1024, 1024);
  wcvt_t<<<dim3(16, 32), 256, 0, stream>>>(Wq,            WqT,            1024, 512);
  wcvt_t<<<dim3(16, 32), 256, 0, stream>>>(Wq + 524288,   WqT + 524288,   1024, 512);
  wcvt_t<<<dim3(16, 32), 256, 0, stream>>>(Wk,            WkT,            1024, 512);
  wcvt_t<<<dim3(16, 32), 256, 0, stream>>>(Wk + 524288,   WkT + 524288,   1024, 512);
  wcvt_t<<<dim3(32, 32), 256, 0, stream>>>(Wc,            WcT,            1024, 1024);
  wcvt_t<<<dim3(32, 32), 256, 0, stream>>>(Wc + 1048576,  WcT + 1048576,  1024, 1024);

  const int NC = 32 / C;

  // embedding: x = relu(node @ Wemb + bemb), chunked (node bf16 staged in xbT slot)
  for (int ch = 0; ch < NC; ++ch) {
    long b0 = (long)ch * C;
    cvt_bf16_k<<<C * 1024, 256, 0, stream>>>(node + b0 * 1048576, xbT);
    gemm_bt<0><<<dim3(8, C * 8, 1), 256, 0, stream>>>(xbT, WembT, xb + b0 * 1048576,
                                                      bemb, 1024, 1024, 0, 0, 0);
  }

  for (int l = 0; l < 2; ++l) {
    for (int ch = 0; ch < NC; ++ch) {
      long b0 = (long)ch * C;
      short* xbc = xb + b0 * 1048576;
      // xbT[c] = x[c]^T
      transpose_bf16<<<dim3(16, 16, C), 256, 0, stream>>>(xbc, xbT);
      // q, k
      gemm_bt<1><<<dim3(4, C * 8, 1), 256, 0, stream>>>(xbc, WqT + l * 524288, q,
                                                        bq + l * 512, 512, 1024, 0, 0, 0);
      gemm_bt<1><<<dim3(4, C * 8, 1), 256, 0, stream>>>(xbc, WkT + l * 524288, k,
                                                        bk + l * 512, 512, 1024, 0, 0, 0);
      // scores = q @ k^T (raw; 1/sqrt(512) applied in softmax)
      gemm_bt<2><<<dim3(8, 8, C), 256, 0, stream>>>(q, k, sc, nullptr,
                                                    1024, 512, 524288, 524288, 1048576);
      // attn = softmax(mask(scores)) in-place
      softmax_mask<<<C * 1024, 256, 0, stream>>>(sc, rel + b0 * 1048576);
      // ctx = attn @ x  (Bt = x^T)
      gemm_bt<2><<<dim3(8, 8, C), 256, 0, stream>>>(sc, xbT, ctx, nullptr,
                                                    1024, 1024, 1048576, 1048576, 1048576);
      // ctx2 = ctx @ Wc (flat M = C*1024)
      gemm_bt<2><<<dim3(8, C * 8, 1), 256, 0, stream>>>(ctx, WcT + l * 1048576, ctx2,
                                                        nullptr, 1024, 1024, 0, 0, 0);
      // x = LN(x + ctx2); also writes f32 rows to out (layer 1 overwrite is final)
      ln_res<<<C * 1024, 256, 0, stream>>>(xbc, ctx2, lng + l * 1024, lnb + l * 1024,
                                           out + b0 * 1048576);
    }
  }
}

// Round 3
// 1461.880 us; speedup vs baseline: 1.0977x; 1.0977x over previous
//
#include <hip/hip_runtime.h>

// GCNEncoder: B=32, N=1024, D=1024, L=2, D_FF=512
// bf16 MFMA (16x16x32) GEMMs, f32 accumulate; softmax/LN reduce in f32.
// R3: XCD-affinity grid mapping, fused q|k GEMM, rel bitmask, vectorized
// transpose (xor-swizzled LDS), dead-write elimination in ln_res.

#define SM_SCALE 0.04419417382415922f  // 1/sqrt(512)

using bf16x8 = __attribute__((ext_vector_type(8))) short;
using f32x4  = __attribute__((ext_vector_type(4))) float;

__device__ __forceinline__ short f2bf(float f) {
  union { float f; unsigned u; } x; x.f = f;
  unsigned r = x.u + 0x7fffu + ((x.u >> 16) & 1u);  // RNE
  return (short)(r >> 16);
}
__device__ __forceinline__ float bf2f(short s) {
  union { unsigned u; float f; } x;
  x.u = ((unsigned)(unsigned short)s) << 16;
  return x.f;
}

typedef const __attribute__((address_space(1))) void* gp1_t;
typedef __attribute__((address_space(3))) void* lp3_t;
__device__ __forceinline__ void ld_lds16(const void* g, void* l) {
  __builtin_amdgcn_global_load_lds((gp1_t)g, (lp3_t)l, 16, 0, 0);
}

// ---------------- C(bf16) = A (MxK, row stride lda) * Bt^T (Bt NxK, stride ldb)
// MODE 0: relu(acc+bias)  MODE 1: acc+bias  MODE 2: acc
// BATCHED: grid (C, N/128, M/128)  -> batch on x => XCD owns whole batches
// flat:    grid (1, M/128, N/128)  -> m-tile on y => XCD owns m-strips, weight B shared
template <int MODE, bool BATCHED>
__global__ __launch_bounds__(256) void gemm_bt(
    const short* __restrict__ A, const short* __restrict__ Bt,
    short* __restrict__ o16, const float* __restrict__ bias,
    int N, int K, long lda, long ldb, long sA, long sB, long sC)
{
  __shared__ __align__(16) short As[128 * 32];
  __shared__ __align__(16) short Bs[128 * 32];
  const int tid  = threadIdx.x;
  const int lane = tid & 63;
  const int wave = tid >> 6;
  const int wm = wave & 1, wn = wave >> 1;
  const int l15 = lane & 15, quad = lane >> 4;
  int bz, bmt, bnt;
  if (BATCHED) { bz = blockIdx.x; bnt = blockIdx.y; bmt = blockIdx.z; }
  else         { bz = 0;          bmt = blockIdx.y; bnt = blockIdx.z; }
  const long m0 = (long)bmt * 128;
  const long n0 = (long)bnt * 128;
  A  += (long)bz * sA;
  Bt += (long)bz * sB;

  const int srow = tid >> 2;          // 0..63
  const int scol = (tid & 3) * 8;     // 0,8,16,24
  const short* pa0 = A  + (m0 + srow) * lda + scol;
  const short* pa1 = pa0 + 64 * lda;
  const short* pb0 = Bt + (n0 + srow) * ldb + scol;
  const short* pb1 = pb0 + 64 * ldb;
  char* la = (char*)As + wave * 1024;   // wave-uniform LDS base (lane*16 implicit)
  char* lb = (char*)Bs + wave * 1024;

  f32x4 acc[4][4];
  const f32x4 z4 = {0.f, 0.f, 0.f, 0.f};
#pragma unroll
  for (int i = 0; i < 4; i++)
#pragma unroll
    for (int j = 0; j < 4; j++) acc[i][j] = z4;

  const int aoff = (wm * 64 + l15) * 32 + quad * 8;
  const int boff = (wn * 64 + l15) * 32 + quad * 8;

  for (int k0 = 0; k0 < K; k0 += 32) {
    __syncthreads();
    ld_lds16(pa0, la);
    ld_lds16(pa1, la + 4096);
    ld_lds16(pb0, lb);
    ld_lds16(pb1, lb + 4096);
    pa0 += 32; pa1 += 32; pb0 += 32; pb1 += 32;
    __syncthreads();
    bf16x8 af[4], bfr[4];
#pragma unroll
    for (int mt = 0; mt < 4; ++mt) af[mt] = *(const bf16x8*)(As + aoff + mt * 512);
#pragma unroll
    for (int nt = 0; nt < 4; ++nt) bfr[nt] = *(const bf16x8*)(Bs + boff + nt * 512);
#pragma unroll
    for (int mt = 0; mt < 4; ++mt)
#pragma unroll
      for (int nt = 0; nt < 4; ++nt)
        acc[mt][nt] = __builtin_amdgcn_mfma_f32_16x16x32_bf16(af[mt], bfr[nt], acc[mt][nt], 0, 0, 0);
  }

  const long cbase = (long)bz * sC;
#pragma unroll
  for (int mt = 0; mt < 4; ++mt) {
#pragma unroll
    for (int nt = 0; nt < 4; ++nt) {
      const long col = n0 + wn * 64 + nt * 16 + l15;
      float bv = 0.f;
      if (MODE <= 1) bv = bias[col];
#pragma unroll
      for (int i = 0; i < 4; i++) {
        const long row = m0 + wm * 64 + mt * 16 + quad * 4 + i;
        float v = acc[mt][nt][i];
        if (MODE <= 1) v += bv;
        if (MODE == 0) v = fmaxf(v, 0.f);
        o16[cbase + row * (long)N + col] = f2bf(v);
      }
    }
  }
}

// ---------------- f32 -> bf16 (grid: blocks*1024 == n)
__global__ __launch_bounds__(256) void cvt_bf16_k(const float* __restrict__ src,
                                                  short* __restrict__ dst) {
  long i = ((long)blockIdx.x * 256 + threadIdx.x) * 4;
  float4 v = *(const float4*)(src + i);
  short4 o;
  o.x = f2bf(v.x); o.y = f2bf(v.y); o.z = f2bf(v.z); o.w = f2bf(v.w);
  *(short4*)(dst + i) = o;
}

// ---------------- weight convert + transpose: dst[n][k] = bf16(src[k][n])
__global__ __launch_bounds__(256) void wcvt_t(const float* __restrict__ src,
                                              short* __restrict__ dst, int K, int N) {
  __shared__ float tile[32][33];
  int n0 = blockIdx.x * 32, k0 = blockIdx.y * 32;
  int tx = threadIdx.x & 31, ty = threadIdx.x >> 5;
#pragma unroll
  for (int j = 0; j < 4; j++) tile[ty + 8 * j][tx] = src[(long)(k0 + ty + 8 * j) * N + n0 + tx];
  __syncthreads();
#pragma unroll
  for (int j = 0; j < 4; j++) dst[(long)(n0 + ty + 8 * j) * K + k0 + tx] = f2bf(tile[tx][ty + 8 * j]);
}

// ---------------- bias concat: dst[0:512)=a, dst[512:1024)=b
__global__ void concat_bias(const float* __restrict__ a, const float* __restrict__ b,
                            float* __restrict__ dst) {
  int t = threadIdx.x;
  dst[t] = a[t];
  dst[512 + t] = b[t];
}

// ---------------- rel_edges -> bitmask (bit set = keep). One row (1024) per block.
__global__ __launch_bounds__(256) void mask_build(const float* __restrict__ rel,
                                                  unsigned long long* __restrict__ bits) {
  long row = blockIdx.x;
  const float* r = rel + row * 1024;
  unsigned long long* mrow = bits + row * 16;
  int t = threadIdx.x;
#pragma unroll
  for (int j = 0; j < 4; j++) {
    float v = r[t + 256 * j];
    unsigned long long m = __ballot(v != 0.f);
    if ((t & 63) == 0) mrow[(t >> 6) + 4 * j] = m;
  }
}

// ---------------- per-batch bf16 transpose, 64x64 tiles, 16B global IO,
// xor-swizzled LDS (2-way max conflict). dst[z][d][i] = src[z][i][d].
__global__ __launch_bounds__(256) void transpose_bf16(const short* __restrict__ src,
                                                      short* __restrict__ dst) {
  __shared__ short tile[64 * 64];
  long base = (long)blockIdx.z * 1048576L;
  int i0 = blockIdx.y * 64, d0 = blockIdx.x * 64;
  int seg = threadIdx.x & 7;    // 8 shorts per segment
  int r   = threadIdx.x >> 3;   // 0..31
#pragma unroll
  for (int p = 0; p < 2; ++p) {
    int rr = r + 32 * p;
    bf16x8 v = *(const bf16x8*)(src + base + (long)(i0 + rr) * 1024 + d0 + seg * 8);
    // logical tile[d'][i'] with d'=seg*8+j, i'=rr; phys col group = (i'>>3) ^ (d'>>3)
#pragma unroll
    for (int j = 0; j < 8; ++j)
      tile[(seg * 8 + j) * 64 + (((rr >> 3) ^ seg) * 8) + (rr & 7)] = v[j];
  }
  __syncthreads();
#pragma unroll
  for (int p = 0; p < 2; ++p) {
    int dd = r + 32 * p;
    bf16x8 v = *(const bf16x8*)&tile[dd * 64 + ((seg ^ ((dd >> 3) & 7)) * 8)];
    *(bf16x8*)(dst + base + (long)(d0 + dd) * 1024 + i0 + seg * 8) = v;
  }
}

// ---------------- masked softmax in-place on bf16 scores (scale + mask from bits)
__global__ __launch_bounds__(256) void softmax_mask(short* __restrict__ sc,
                                                    const unsigned long long* __restrict__ bits) {
  __shared__ float red[8];
  long row = blockIdx.x;
  short* s = sc + row * 1024;
  const unsigned long long* mrow = bits + row * 16;
  int t = threadIdx.x, lane = t & 63, wave = t >> 6;
  float v[4];
  float mx = -3e38f;
#pragma unroll
  for (int j = 0; j < 4; j++) {
    int i = t + 256 * j;
    unsigned long long w = mrow[4 * j + wave];
    bool keep = (w >> lane) & 1ULL;
    v[j] = keep ? bf2f(s[i]) * SM_SCALE : -3e38f;
    mx = fmaxf(mx, v[j]);
  }
#pragma unroll
  for (int o = 32; o > 0; o >>= 1) mx = fmaxf(mx, __shfl_xor(mx, o, 64));
  if (lane == 0) red[wave] = mx;
  __syncthreads();
  mx = fmaxf(fmaxf(red[0], red[1]), fmaxf(red[2], red[3]));
  float e[4], sum = 0.f;
#pragma unroll
  for (int j = 0; j < 4; j++) {
    e[j] = (v[j] > -1e38f) ? __expf(v[j] - mx) : 0.f;
    sum += e[j];
  }
#pragma unroll
  for (int o = 32; o > 0; o >>= 1) sum += __shfl_xor(sum, o, 64);
  if (lane == 0) red[4 + wave] = sum;
  __syncthreads();
  sum = red[4] + red[5] + red[6] + red[7];
  float inv = 1.f / sum;
#pragma unroll
  for (int j = 0; j < 4; j++) s[t + 256 * j] = f2bf(e[j] * inv);
}

// ---------------- residual + LayerNorm. WOUT: write f32 out; WXB: update xb bf16.
template <bool WOUT, bool WXB>
__global__ __launch_bounds__(256) void ln_res(short* __restrict__ xb,
                                              const short* __restrict__ dlt,
                                              const float* __restrict__ g,
                                              const float* __restrict__ bb,
                                              float* __restrict__ o32) {
  __shared__ float red[8];
  long row = blockIdx.x;
  short* xr = xb + row * 1024;
  const short* dr = dlt + row * 1024;
  float* orow = o32 + row * 1024;
  int t = threadIdx.x, lane = t & 63, wave = t >> 6;
  float y[4], s = 0.f;
#pragma unroll
  for (int j = 0; j < 4; j++) {
    int i = t + 256 * j;
    y[j] = bf2f(xr[i]) + bf2f(dr[i]);
    s += y[j];
  }
#pragma unroll
  for (int o = 32; o > 0; o >>= 1) s += __shfl_xor(s, o, 64);
  if (lane == 0) red[wave] = s;
  __syncthreads();
  s = red[0] + red[1] + red[2] + red[3];
  float mean = s * (1.f / 1024.f);
  float s2 = 0.f;
#pragma unroll
  for (int j = 0; j < 4; j++) { float d = y[j] - mean; s2 += d * d; }
#pragma unroll
  for (int o = 32; o > 0; o >>= 1) s2 += __shfl_xor(s2, o, 64);
  if (lane == 0) red[4 + wave] = s2;
  __syncthreads();
  s2 = red[4] + red[5] + red[6] + red[7];
  float rs = rsqrtf(s2 * (1.f / 1024.f) + 1e-5f);
#pragma unroll
  for (int j = 0; j < 4; j++) {
    int i = t + 256 * j;
    float o = (y[j] - mean) * rs * g[i] + bb[i];
    if (WOUT) orow[i] = o;
    if (WXB)  xr[i] = f2bf(o);
  }
}

extern "C" void kernel_launch(void* const* d_in, const int* in_sizes, int n_in,
                              void* d_out, int out_size, void* d_ws, size_t ws_size,
                              hipStream_t stream) {
  const float* node = (const float*)d_in[0];
  const float* rel  = (const float*)d_in[1];
  const float* Wemb = (const float*)d_in[2];
  const float* bemb = (const float*)d_in[3];
  const float* Wq   = (const float*)d_in[4];
  const float* bq   = (const float*)d_in[5];
  const float* Wk   = (const float*)d_in[6];
  const float* bk   = (const float*)d_in[7];
  const float* Wc   = (const float*)d_in[8];
  const float* lng  = (const float*)d_in[9];
  const float* lnb  = (const float*)d_in[10];
  float* out = (float*)d_out;

  // chunk C: need 81797120 + 8388608*C bytes
  int C = 0;
  for (int c = 32; c >= 1; c >>= 1)
    if (81797120ULL + 8388608ULL * (unsigned long long)c <= (unsigned long long)ws_size) { C = c; break; }
  if (C == 0) return;

  char* ws = (char*)d_ws;
  short* xb    = (short*)ws;                        // 32x1024x1024 bf16 (64 MB)
  short* WembT = (short*)(ws + 67108864);           // [1024][1024]
  short* WqkT  = (short*)(ws + 69206016);           // 2 x [1024][1024] (q rows 0..511, k rows 512..1023)
  short* WcT   = (short*)(ws + 73400320);           // 2 x [1024][1024]
  float* bqk   = (float*)(ws + 77594624);           // 2 x [1024]
  unsigned long long* mbits = (unsigned long long*)(ws + 77602816);  // 32*1024*16 u64 (4 MB)
  char* chunk  = ws + 81797120;
  short* xbT  = (short*)chunk;                          // C x 1024x1024
  short* sc   = (short*)(chunk + (size_t)C * 2097152);  // C x 1024x1024 (scores->attn)
  short* ctx  = (short*)(chunk + (size_t)C * 4194304);  // C x 1024x1024
  short* qk   = (short*)(chunk + (size_t)C * 6291456);  // C x 1024x1024 (q|k)
  short* ctx2 = qk;                                     // alias (qk dead after scores)

  // prep (tiny)
  wcvt_t<<<dim3(32, 32), 256, 0, stream>>>(Wemb, WembT, 1024, 1024);
  for (int l = 0; l < 2; ++l) {
    wcvt_t<<<dim3(16, 32), 256, 0, stream>>>(Wq + l * 524288, WqkT + l * 1048576,          1024, 512);
    wcvt_t<<<dim3(16, 32), 256, 0, stream>>>(Wk + l * 524288, WqkT + l * 1048576 + 524288, 1024, 512);
    wcvt_t<<<dim3(32, 32), 256, 0, stream>>>(Wc + l * 1048576, WcT + l * 1048576, 1024, 1024);
    concat_bias<<<1, 512, 0, stream>>>(bq + l * 512, bk + l * 512, bqk + l * 1024);
  }
  mask_build<<<32768, 256, 0, stream>>>(rel, mbits);

  const int NC = 32 / C;

  // embedding: x = relu(node @ Wemb + bemb)
  for (int ch = 0; ch < NC; ++ch) {
    long b0 = (long)ch * C;
    cvt_bf16_k<<<C * 1024, 256, 0, stream>>>(node + b0 * 1048576, xbT);
    gemm_bt<0, false><<<dim3(1, C * 8, 8), 256, 0, stream>>>(
        xbT, WembT, xb + b0 * 1048576, bemb, 1024, 1024, 1024, 1024, 0, 0, 0);
  }

  for (int l = 0; l < 2; ++l) {
    for (int ch = 0; ch < NC; ++ch) {
      long b0 = (long)ch * C;
      short* xbc = xb + b0 * 1048576;
      // xbT[c] = x[c]^T
      transpose_bf16<<<dim3(16, 16, C), 256, 0, stream>>>(xbc, xbT);
      // q|k fused: [C*1024][1024]
      gemm_bt<1, false><<<dim3(1, C * 8, 8), 256, 0, stream>>>(
          xbc, WqkT + l * 1048576, qk, bqk + l * 1024, 1024, 1024, 1024, 1024, 0, 0, 0);
      // scores = q @ k^T (batched; scale in softmax)
      gemm_bt<2, true><<<dim3(C, 8, 8), 256, 0, stream>>>(
          qk, qk + 512, sc, nullptr, 1024, 512, 1024, 1024, 1048576, 1048576, 1048576);
      // attn = softmax(mask(scores)) in-place, mask from bits
      softmax_mask<<<C * 1024, 256, 0, stream>>>(sc, mbits + b0 * 16384);
      // ctx = attn @ x (Bt = x^T), batched
      gemm_bt<2, true><<<dim3(C, 8, 8), 256, 0, stream>>>(
          sc, xbT, ctx, nullptr, 1024, 1024, 1024, 1024, 1048576, 1048576, 1048576);
      // ctx2 = ctx @ Wc (flat)
      gemm_bt<2, false><<<dim3(1, C * 8, 8), 256, 0, stream>>>(
          ctx, WcT + l * 1048576, ctx2, nullptr, 1024, 1024, 1024, 1024, 0, 0, 0);
      // x = LN(x + ctx2): l0 -> xb only; l1 -> out only
      if (l == 0)
        ln_res<false, true><<<C * 1024, 256, 0, stream>>>(
            xbc, ctx2, lng, lnb, nullptr);
      else
        ln_res<true, false><<<C * 1024, 256, 0, stream>>>(
            xbc, ctx2, lng + 1024, lnb + 1024, out + b0 * 1048576);
    }
  }
}

// Round 4
// 1428.494 us; speedup vs baseline: 1.1233x; 1.0234x over previous
//
#include <hip/hip_runtime.h>

// GCNEncoder: B=32, N=1024, D=1024, L=2, D_FF=512
// bf16 MFMA (16x16x32) GEMMs, f32 accumulate; softmax/LN reduce in f32.
// R4: BK=64 K-loop (half the barrier drains) + xor-swizzled LDS layout
// (conflict-free ds_read_b128: 2 lanes/bank). XCD-affinity grids kept.

#define SM_SCALE 0.04419417382415922f  // 1/sqrt(512)

using bf16x8 = __attribute__((ext_vector_type(8))) short;
using f32x4  = __attribute__((ext_vector_type(4))) float;

__device__ __forceinline__ short f2bf(float f) {
  union { float f; unsigned u; } x; x.f = f;
  unsigned r = x.u + 0x7fffu + ((x.u >> 16) & 1u);  // RNE
  return (short)(r >> 16);
}
__device__ __forceinline__ float bf2f(short s) {
  union { unsigned u; float f; } x;
  x.u = ((unsigned)(unsigned short)s) << 16;
  return x.f;
}

typedef const __attribute__((address_space(1))) void* gp1_t;
typedef __attribute__((address_space(3))) void* lp3_t;
__device__ __forceinline__ void ld_lds16(const void* g, void* l) {
  __builtin_amdgcn_global_load_lds((gp1_t)g, (lp3_t)l, 16, 0, 0);
}

// ---------------- C(bf16) = A (MxK, row stride lda) * Bt^T (Bt NxK, stride ldb)
// MODE 0: relu(acc+bias)  MODE 1: acc+bias  MODE 2: acc
// BATCHED: grid (C, N/128, M/128); flat: grid (1, M/128, N/128)
// LDS: tiles 128x64 shorts; column-group cg (8 shorts) of row r stored at
// phys cg^(r&7)  ->  ds_read_b128 hits each bank exactly twice (free).
template <int MODE, bool BATCHED>
__global__ __launch_bounds__(256) void gemm_bt(
    const short* __restrict__ A, const short* __restrict__ Bt,
    short* __restrict__ o16, const float* __restrict__ bias,
    int N, int K, long lda, long ldb, long sA, long sB, long sC)
{
  __shared__ __align__(16) short As[128 * 64];
  __shared__ __align__(16) short Bs[128 * 64];
  const int tid  = threadIdx.x;
  const int lane = tid & 63;
  const int wave = tid >> 6;
  const int wm = wave & 1, wn = wave >> 1;
  const int l15 = lane & 15, quad = lane >> 4;
  int bz, bmt, bnt;
  if (BATCHED) { bz = blockIdx.x; bnt = blockIdx.y; bmt = blockIdx.z; }
  else         { bz = 0;          bmt = blockIdx.y; bnt = blockIdx.z; }
  const long m0 = (long)bmt * 128;
  const long n0 = (long)bnt * 128;
  A  += (long)bz * sA + m0 * lda;
  Bt += (long)bz * sB + n0 * ldb;

  // staging: call s (s=0..3) covers rows s*32 + wave*8 + (lane>>3);
  // lane loads logical col-group (lane&7)^(lane>>3) so that after the
  // lane*16 DMA placement, phys cg == logical cg ^ (row&7).
  const int sr  = wave * 8 + (lane >> 3);
  const int scl = ((lane & 7) ^ (lane >> 3)) * 8;
  const short* pa = A  + (long)sr * lda + scl;
  const short* pb = Bt + (long)sr * ldb + scl;
  char* la = (char*)As + wave * 1024;
  char* lb = (char*)Bs + wave * 1024;

  f32x4 acc[4][4];
  const f32x4 z4 = {0.f, 0.f, 0.f, 0.f};
#pragma unroll
  for (int i = 0; i < 4; i++)
#pragma unroll
    for (int j = 0; j < 4; j++) acc[i][j] = z4;

  for (int k0 = 0; k0 < K; k0 += 64) {
    __syncthreads();                      // prior frag reads done
#pragma unroll
    for (int s = 0; s < 4; ++s) {
      ld_lds16(pa + (long)s * 32 * lda + k0, la + s * 4096);
      ld_lds16(pb + (long)s * 32 * ldb + k0, lb + s * 4096);
    }
    __syncthreads();                      // staging drained
#pragma unroll
    for (int h = 0; h < 2; ++h) {
      bf16x8 af[4], bfr[4];
      const int swz = ((h * 4 + quad) ^ (l15 & 7)) * 8;
#pragma unroll
      for (int mt = 0; mt < 4; ++mt)
        af[mt] = *(const bf16x8*)(As + (wm * 64 + mt * 16 + l15) * 64 + swz);
#pragma unroll
      for (int nt = 0; nt < 4; ++nt)
        bfr[nt] = *(const bf16x8*)(Bs + (wn * 64 + nt * 16 + l15) * 64 + swz);
#pragma unroll
      for (int mt = 0; mt < 4; ++mt)
#pragma unroll
        for (int nt = 0; nt < 4; ++nt)
          acc[mt][nt] = __builtin_amdgcn_mfma_f32_16x16x32_bf16(af[mt], bfr[nt], acc[mt][nt], 0, 0, 0);
    }
  }

  const long cbase = (long)bz * sC;
#pragma unroll
  for (int mt = 0; mt < 4; ++mt) {
#pragma unroll
    for (int nt = 0; nt < 4; ++nt) {
      const long col = n0 + wn * 64 + nt * 16 + l15;
      float bv = 0.f;
      if (MODE <= 1) bv = bias[col];
#pragma unroll
      for (int i = 0; i < 4; i++) {
        const long row = m0 + wm * 64 + mt * 16 + quad * 4 + i;
        float v = acc[mt][nt][i];
        if (MODE <= 1) v += bv;
        if (MODE == 0) v = fmaxf(v, 0.f);
        o16[cbase + row * (long)N + col] = f2bf(v);
      }
    }
  }
}

// ---------------- f32 -> bf16 (grid: blocks*1024 == n)
__global__ __launch_bounds__(256) void cvt_bf16_k(const float* __restrict__ src,
                                                  short* __restrict__ dst) {
  long i = ((long)blockIdx.x * 256 + threadIdx.x) * 4;
  float4 v = *(const float4*)(src + i);
  short4 o;
  o.x = f2bf(v.x); o.y = f2bf(v.y); o.z = f2bf(v.z); o.w = f2bf(v.w);
  *(short4*)(dst + i) = o;
}

// ---------------- weight convert + transpose: dst[n][k] = bf16(src[k][n])
__global__ __launch_bounds__(256) void wcvt_t(const float* __restrict__ src,
                                              short* __restrict__ dst, int K, int N) {
  __shared__ float tile[32][33];
  int n0 = blockIdx.x * 32, k0 = blockIdx.y * 32;
  int tx = threadIdx.x & 31, ty = threadIdx.x >> 5;
#pragma unroll
  for (int j = 0; j < 4; j++) tile[ty + 8 * j][tx] = src[(long)(k0 + ty + 8 * j) * N + n0 + tx];
  __syncthreads();
#pragma unroll
  for (int j = 0; j < 4; j++) dst[(long)(n0 + ty + 8 * j) * K + k0 + tx] = f2bf(tile[tx][ty + 8 * j]);
}

// ---------------- bias concat
__global__ void concat_bias(const float* __restrict__ a, const float* __restrict__ b,
                            float* __restrict__ dst) {
  int t = threadIdx.x;
  dst[t] = a[t];
  dst[512 + t] = b[t];
}

// ---------------- rel_edges -> bitmask (bit set = keep)
__global__ __launch_bounds__(256) void mask_build(const float* __restrict__ rel,
                                                  unsigned long long* __restrict__ bits) {
  long row = blockIdx.x;
  const float* r = rel + row * 1024;
  unsigned long long* mrow = bits + row * 16;
  int t = threadIdx.x;
#pragma unroll
  for (int j = 0; j < 4; j++) {
    float v = r[t + 256 * j];
    unsigned long long m = __ballot(v != 0.f);
    if ((t & 63) == 0) mrow[(t >> 6) + 4 * j] = m;
  }
}

// ---------------- per-batch bf16 transpose, 64x64 tiles, 16B IO, xor-swizzled LDS
__global__ __launch_bounds__(256) void transpose_bf16(const short* __restrict__ src,
                                                      short* __restrict__ dst) {
  __shared__ short tile[64 * 64];
  long base = (long)blockIdx.z * 1048576L;
  int i0 = blockIdx.y * 64, d0 = blockIdx.x * 64;
  int seg = threadIdx.x & 7;
  int r   = threadIdx.x >> 3;
#pragma unroll
  for (int p = 0; p < 2; ++p) {
    int rr = r + 32 * p;
    bf16x8 v = *(const bf16x8*)(src + base + (long)(i0 + rr) * 1024 + d0 + seg * 8);
#pragma unroll
    for (int j = 0; j < 8; ++j)
      tile[(seg * 8 + j) * 64 + (((rr >> 3) ^ seg) * 8) + (rr & 7)] = v[j];
  }
  __syncthreads();
#pragma unroll
  for (int p = 0; p < 2; ++p) {
    int dd = r + 32 * p;
    bf16x8 v = *(const bf16x8*)&tile[dd * 64 + ((seg ^ ((dd >> 3) & 7)) * 8)];
    *(bf16x8*)(dst + base + (long)(d0 + dd) * 1024 + i0 + seg * 8) = v;
  }
}

// ---------------- masked softmax in-place on bf16 scores
__global__ __launch_bounds__(256) void softmax_mask(short* __restrict__ sc,
                                                    const unsigned long long* __restrict__ bits) {
  __shared__ float red[8];
  long row = blockIdx.x;
  short* s = sc + row * 1024;
  const unsigned long long* mrow = bits + row * 16;
  int t = threadIdx.x, lane = t & 63, wave = t >> 6;
  float v[4];
  float mx = -3e38f;
#pragma unroll
  for (int j = 0; j < 4; j++) {
    int i = t + 256 * j;
    unsigned long long w = mrow[4 * j + wave];
    bool keep = (w >> lane) & 1ULL;
    v[j] = keep ? bf2f(s[i]) * SM_SCALE : -3e38f;
    mx = fmaxf(mx, v[j]);
  }
#pragma unroll
  for (int o = 32; o > 0; o >>= 1) mx = fmaxf(mx, __shfl_xor(mx, o, 64));
  if (lane == 0) red[wave] = mx;
  __syncthreads();
  mx = fmaxf(fmaxf(red[0], red[1]), fmaxf(red[2], red[3]));
  float e[4], sum = 0.f;
#pragma unroll
  for (int j = 0; j < 4; j++) {
    e[j] = (v[j] > -1e38f) ? __expf(v[j] - mx) : 0.f;
    sum += e[j];
  }
#pragma unroll
  for (int o = 32; o > 0; o >>= 1) sum += __shfl_xor(sum, o, 64);
  if (lane == 0) red[4 + wave] = sum;
  __syncthreads();
  sum = red[4] + red[5] + red[6] + red[7];
  float inv = 1.f / sum;
#pragma unroll
  for (int j = 0; j < 4; j++) s[t + 256 * j] = f2bf(e[j] * inv);
}

// ---------------- residual + LayerNorm. WOUT: write f32 out; WXB: update xb bf16.
template <bool WOUT, bool WXB>
__global__ __launch_bounds__(256) void ln_res(short* __restrict__ xb,
                                              const short* __restrict__ dlt,
                                              const float* __restrict__ g,
                                              const float* __restrict__ bb,
                                              float* __restrict__ o32) {
  __shared__ float red[8];
  long row = blockIdx.x;
  short* xr = xb + row * 1024;
  const short* dr = dlt + row * 1024;
  float* orow = o32 + row * 1024;
  int t = threadIdx.x, lane = t & 63, wave = t >> 6;
  float y[4], s = 0.f;
#pragma unroll
  for (int j = 0; j < 4; j++) {
    int i = t + 256 * j;
    y[j] = bf2f(xr[i]) + bf2f(dr[i]);
    s += y[j];
  }
#pragma unroll
  for (int o = 32; o > 0; o >>= 1) s += __shfl_xor(s, o, 64);
  if (lane == 0) red[wave] = s;
  __syncthreads();
  s = red[0] + red[1] + red[2] + red[3];
  float mean = s * (1.f / 1024.f);
  float s2 = 0.f;
#pragma unroll
  for (int j = 0; j < 4; j++) { float d = y[j] - mean; s2 += d * d; }
#pragma unroll
  for (int o = 32; o > 0; o >>= 1) s2 += __shfl_xor(s2, o, 64);
  if (lane == 0) red[4 + wave] = s2;
  __syncthreads();
  s2 = red[4] + red[5] + red[6] + red[7];
  float rs = rsqrtf(s2 * (1.f / 1024.f) + 1e-5f);
#pragma unroll
  for (int j = 0; j < 4; j++) {
    int i = t + 256 * j;
    float o = (y[j] - mean) * rs * g[i] + bb[i];
    if (WOUT) orow[i] = o;
    if (WXB)  xr[i] = f2bf(o);
  }
}

extern "C" void kernel_launch(void* const* d_in, const int* in_sizes, int n_in,
                              void* d_out, int out_size, void* d_ws, size_t ws_size,
                              hipStream_t stream) {
  const float* node = (const float*)d_in[0];
  const float* rel  = (const float*)d_in[1];
  const float* Wemb = (const float*)d_in[2];
  const float* bemb = (const float*)d_in[3];
  const float* Wq   = (const float*)d_in[4];
  const float* bq   = (const float*)d_in[5];
  const float* Wk   = (const float*)d_in[6];
  const float* bk   = (const float*)d_in[7];
  const float* Wc   = (const float*)d_in[8];
  const float* lng  = (const float*)d_in[9];
  const float* lnb  = (const float*)d_in[10];
  float* out = (float*)d_out;

  // chunk C: need 81797120 + 8388608*C bytes
  int C = 0;
  for (int c = 32; c >= 1; c >>= 1)
    if (81797120ULL + 8388608ULL * (unsigned long long)c <= (unsigned long long)ws_size) { C = c; break; }
  if (C == 0) return;

  char* ws = (char*)d_ws;
  short* xb    = (short*)ws;                        // 32x1024x1024 bf16 (64 MB)
  short* WembT = (short*)(ws + 67108864);           // [1024][1024]
  short* WqkT  = (short*)(ws + 69206016);           // 2 x [1024][1024] (q|k)
  short* WcT   = (short*)(ws + 73400320);           // 2 x [1024][1024]
  float* bqk   = (float*)(ws + 77594624);           // 2 x [1024]
  unsigned long long* mbits = (unsigned long long*)(ws + 77602816);  // 4 MB
  char* chunk  = ws + 81797120;
  short* xbT  = (short*)chunk;                          // C x 1024x1024
  short* sc   = (short*)(chunk + (size_t)C * 2097152);  // C x 1024x1024
  short* ctx  = (short*)(chunk + (size_t)C * 4194304);  // C x 1024x1024
  short* qk   = (short*)(chunk + (size_t)C * 6291456);  // C x 1024x1024
  short* ctx2 = qk;                                     // alias

  // prep (tiny)
  wcvt_t<<<dim3(32, 32), 256, 0, stream>>>(Wemb, WembT, 1024, 1024);
  for (int l = 0; l < 2; ++l) {
    wcvt_t<<<dim3(16, 32), 256, 0, stream>>>(Wq + l * 524288, WqkT + l * 1048576,          1024, 512);
    wcvt_t<<<dim3(16, 32), 256, 0, stream>>>(Wk + l * 524288, WqkT + l * 1048576 + 524288, 1024, 512);
    wcvt_t<<<dim3(32, 32), 256, 0, stream>>>(Wc + l * 1048576, WcT + l * 1048576, 1024, 1024);
    concat_bias<<<1, 512, 0, stream>>>(bq + l * 512, bk + l * 512, bqk + l * 1024);
  }
  mask_build<<<32768, 256, 0, stream>>>(rel, mbits);

  const int NC = 32 / C;

  // embedding: x = relu(node @ Wemb + bemb)
  for (int ch = 0; ch < NC; ++ch) {
    long b0 = (long)ch * C;
    cvt_bf16_k<<<C * 1024, 256, 0, stream>>>(node + b0 * 1048576, xbT);
    gemm_bt<0, false><<<dim3(1, C * 8, 8), 256, 0, stream>>>(
        xbT, WembT, xb + b0 * 1048576, bemb, 1024, 1024, 1024, 1024, 0, 0, 0);
  }

  for (int l = 0; l < 2; ++l) {
    for (int ch = 0; ch < NC; ++ch) {
      long b0 = (long)ch * C;
      short* xbc = xb + b0 * 1048576;
      transpose_bf16<<<dim3(16, 16, C), 256, 0, stream>>>(xbc, xbT);
      gemm_bt<1, false><<<dim3(1, C * 8, 8), 256, 0, stream>>>(
          xbc, WqkT + l * 1048576, qk, bqk + l * 1024, 1024, 1024, 1024, 1024, 0, 0, 0);
      gemm_bt<2, true><<<dim3(C, 8, 8), 256, 0, stream>>>(
          qk, qk + 512, sc, nullptr, 1024, 512, 1024, 1024, 1048576, 1048576, 1048576);
      softmax_mask<<<C * 1024, 256, 0, stream>>>(sc, mbits + b0 * 16384);
      gemm_bt<2, true><<<dim3(C, 8, 8), 256, 0, stream>>>(
          sc, xbT, ctx, nullptr, 1024, 1024, 1024, 1024, 1048576, 1048576, 1048576);
      gemm_bt<2, false><<<dim3(1, C * 8, 8), 256, 0, stream>>>(
          ctx, WcT + l * 1048576, ctx2, nullptr, 1024, 1024, 1024, 1024, 0, 0, 0);
      if (l == 0)
        ln_res<false, true><<<C * 1024, 256, 0, stream>>>(xbc, ctx2, lng, lnb, nullptr);
      else
        ln_res<true, false><<<C * 1024, 256, 0, stream>>>(xbc, ctx2, lng + 1024, lnb + 1024,
                                                          out + b0 * 1048576);
    }
  }
}